// Round 3
// baseline (494.254 us; speedup 1.0000x reference)
//
#include <hip/hip_runtime.h>
#include <stdint.h>
#include <math.h>

// B=4, T=2048, D=2048, HEADS=16.  Inputs/outputs fp32; internal bf16 MFMA.
//
// Pipeline: cast -> A: kv^T -> T: transpose -> B: scores -> S: softmax ->
//           C: q = a@vT^T -> D: perm(q)@w_dense^T + bias.
//
// GEMM core: 256x256 8-phase schedule (T2+T3+T4+T5), UNROLLED 2 K-tiles/iter:
// compile-time buf, branch-free steady-state body, induction staging pointers
// (+128 elems/iter), LDS reads as base VGPR + immediate offsets.
//
// ROUND-2 BUG FIXED HERE: staging macro previously added kh*32 on top of call
// sites that already folded the kh offset into the literal -> all loop/tail
// kh=1 stagings read K+32 (wrong data), and the tail's read at base+2048
// walked one row past the operand end -> OOB fault on the stage-C A operand
// (last row of sb = last bytes of d_out).  Macro now takes the FULL K-offset;
// kh is used only to select the LDS destination region.  Max in-row read is
// element base(1920)+96+co(<=24)+7 = 2047 for every operand: exactly in-bounds.
//
//  - 512 thr = 8 waves (2M x 4N), per-wave output 128x64 (acc[8][4] f32x4).
//  - BK=64 in two kh-halves of 32; LDS = 2dbuf x {A,B} x [2kh][256r x 32c] bf16
//    = 128 KiB dynamic.  Region granularity = (op, kh) half (16 KiB).
//  - Staging: global_load_lds width=16, LINEAR LDS dest; global source chunk
//    g = (tid&3)^((tid>>3)&3) (involution with read-side XOR) -> 0 bank
//    conflicts (verified round 1).
//  - Steady-state ledger (per iter, tiles t0=2it buf0 / t1=2it+1 buf1),
//    full K-offsets relative to iter base (tile t0 at offset 0):
//      t0P1 stg@96  A(t1,kh1)   t0P2 stg@96  B(t1,kh1) vmcnt(8)->t0.kh1 ready
//      t0P3 stg@128 A(t2,kh0)   t0P4 stg@128 B(t2,kh0) vmcnt(8)->t1.kh0 ready
//      t1P1 stg@160 A(t2,kh1)   t1P2 stg@160 B(t2,kh1) vmcnt(8)->t1.kh1 ready
//      t1P3 stg@192 A(t3,kh0)   t1P4 stg@192 B(t3,kh0) vmcnt(8)->t2.kh0 ready
//    Every stg targets a region whose last reader finished >=1 barrier earlier.
//    Tail (last 2 tiles): stg only A/B@96 (t1,kh1); waits 8 -> 4 -> 0.
//    Prologue: t0 kh0@0, kh1@32 + t1 kh0@64; vmcnt(4).  K % 128 == 0.

typedef __bf16 bf16x8 __attribute__((ext_vector_type(8)));
typedef float  f32x4  __attribute__((ext_vector_type(4)));

typedef __attribute__((address_space(3))) uint32_t lds_u32_t;
typedef __attribute__((address_space(1))) const uint32_t glb_u32_t;

__device__ __forceinline__ float bf2f(uint16_t u) {
  union { uint32_t i; float f; } c; c.i = ((uint32_t)u) << 16; return c.f;
}
__device__ __forceinline__ uint16_t f2bf(float f) {
  union { float f; uint32_t i; } c; c.f = f;
  uint32_t i = c.i;
  return (uint16_t)((i + 0x7fffu + ((i >> 16) & 1u)) >> 16);  // RNE
}

__device__ __forceinline__ void glds16(const uint16_t* g, const char* l) {
  __builtin_amdgcn_global_load_lds((glb_u32_t*)g, (lds_u32_t*)l, 16, 0, 0);
}

#define FENCE() asm volatile("" ::: "memory")
#define BARRIER() do { FENCE(); __builtin_amdgcn_s_barrier(); FENCE(); } while (0)
#define VMCNT(n_) asm volatile("s_waitcnt vmcnt(" #n_ ")" ::: "memory")

// ---- fused fp32 -> bf16 cast over x|w_qk|w_dense -----------------------------
#define NX4 4194304u
#define NW4 2097152u
#define ND4 1048576u
__global__ __launch_bounds__(256) void k_cast_all(
    const float* __restrict__ x, const float* __restrict__ wqk,
    const float* __restrict__ wd, uint16_t* __restrict__ dst) {
  uint32_t i = blockIdx.x * 256 + threadIdx.x;
  float4 v;
  if (i < NX4)            v = reinterpret_cast<const float4*>(x)[i];
  else if (i < NX4 + NW4) v = reinterpret_cast<const float4*>(wqk)[i - NX4];
  else                    v = reinterpret_cast<const float4*>(wd)[i - NX4 - NW4];
  ushort4 o;
  o.x = f2bf(v.x); o.y = f2bf(v.y); o.z = f2bf(v.z); o.w = f2bf(v.w);
  reinterpret_cast<ushort4*>(dst)[i] = o;
}

// ---- 256x256 8-phase GEMM core, 2 K-tiles per iteration ---------------------
// aR0/aR1/bR0/bR1: per-thread staging sources, rows (tid>>2) and (tid>>2)+128
// of the 256-row tile, at k=0, swizzled chunk offset already added.
__device__ __forceinline__ void gemm256_core(
    const uint16_t* aR0, const uint16_t* aR1,
    const uint16_t* bR0, const uint16_t* bR1,
    int K, f32x4 acc[8][4])
{
  extern __shared__ uint4 smem_u4[];
  char* smem = (char*)smem_u4;
  const int tid = threadIdx.x;
  const int w = tid >> 6, l = tid & 63;
  const int wm = (w >> 2) * 128, wn = (w & 3) * 64;
  const int frow = l & 15, fkc = l >> 4;
  // read-side chunk swizzle: chunk' = fkc ^ ((frow>>1)&3)  (fixed per lane)
  const uint32_t chunk = (uint32_t)((fkc ^ ((frow >> 1) & 3)) * 16);
  const uint32_t aBase = (uint32_t)(wm + frow) * 64 + chunk;           // +mi*1024 +kh*16384 +buf*32768
  const uint32_t bBase = 65536u + (uint32_t)(wn + frow) * 64 + chunk;  // +ni*1024 +kh*16384 +buf*32768
  char* lW = smem + (uint32_t)w * 1024u;   // per-wave staging dest base
  const int NIT = K >> 7;                  // iterations of 2 K-tiles; K % 128 == 0

#define LDSA(kh_, buf_, half_) (lW + ((buf_) * 32768u + (kh_) * 16384u + (half_) * 8192u))
#define LDSB(kh_, buf_, half_) (lW + (65536u + (buf_) * 32768u + (kh_) * 16384u + (half_) * 8192u))
// off_ is the FULL K-offset in elements (tile*64 + kh*32); kh_ selects the LDS
// destination region only.
#define STG_A(off_, kh_, buf_) do { \
    glds16(aR0 + (off_), LDSA(kh_, buf_, 0)); \
    glds16(aR1 + (off_), LDSA(kh_, buf_, 1)); } while (0)
#define STG_B(off_, kh_, buf_) do { \
    glds16(bR0 + (off_), LDSB(kh_, buf_, 0)); \
    glds16(bR1 + (off_), LDSB(kh_, buf_, 1)); } while (0)
#define RD_A(mi_, kh_, buf_) \
    (*reinterpret_cast<const bf16x8*>(smem + (aBase + (mi_) * 1024u + (kh_) * 16384u + (buf_) * 32768u)))
#define RD_B(ni_, kh_, buf_) \
    (*reinterpret_cast<const bf16x8*>(smem + (bBase + (ni_) * 1024u + (kh_) * 16384u + (buf_) * 32768u)))
#define MFMA16(m0_) do { \
    acc[(m0_)+0][0] = __builtin_amdgcn_mfma_f32_16x16x32_bf16(a0, b0, acc[(m0_)+0][0], 0, 0, 0); \
    acc[(m0_)+1][0] = __builtin_amdgcn_mfma_f32_16x16x32_bf16(a1, b0, acc[(m0_)+1][0], 0, 0, 0); \
    acc[(m0_)+2][0] = __builtin_amdgcn_mfma_f32_16x16x32_bf16(a2, b0, acc[(m0_)+2][0], 0, 0, 0); \
    acc[(m0_)+3][0] = __builtin_amdgcn_mfma_f32_16x16x32_bf16(a3, b0, acc[(m0_)+3][0], 0, 0, 0); \
    acc[(m0_)+0][1] = __builtin_amdgcn_mfma_f32_16x16x32_bf16(a0, b1, acc[(m0_)+0][1], 0, 0, 0); \
    acc[(m0_)+1][1] = __builtin_amdgcn_mfma_f32_16x16x32_bf16(a1, b1, acc[(m0_)+1][1], 0, 0, 0); \
    acc[(m0_)+2][1] = __builtin_amdgcn_mfma_f32_16x16x32_bf16(a2, b1, acc[(m0_)+2][1], 0, 0, 0); \
    acc[(m0_)+3][1] = __builtin_amdgcn_mfma_f32_16x16x32_bf16(a3, b1, acc[(m0_)+3][1], 0, 0, 0); \
    acc[(m0_)+0][2] = __builtin_amdgcn_mfma_f32_16x16x32_bf16(a0, b2, acc[(m0_)+0][2], 0, 0, 0); \
    acc[(m0_)+1][2] = __builtin_amdgcn_mfma_f32_16x16x32_bf16(a1, b2, acc[(m0_)+1][2], 0, 0, 0); \
    acc[(m0_)+2][2] = __builtin_amdgcn_mfma_f32_16x16x32_bf16(a2, b2, acc[(m0_)+2][2], 0, 0, 0); \
    acc[(m0_)+3][2] = __builtin_amdgcn_mfma_f32_16x16x32_bf16(a3, b2, acc[(m0_)+3][2], 0, 0, 0); \
    acc[(m0_)+0][3] = __builtin_amdgcn_mfma_f32_16x16x32_bf16(a0, b3, acc[(m0_)+0][3], 0, 0, 0); \
    acc[(m0_)+1][3] = __builtin_amdgcn_mfma_f32_16x16x32_bf16(a1, b3, acc[(m0_)+1][3], 0, 0, 0); \
    acc[(m0_)+2][3] = __builtin_amdgcn_mfma_f32_16x16x32_bf16(a2, b3, acc[(m0_)+2][3], 0, 0, 0); \
    acc[(m0_)+3][3] = __builtin_amdgcn_mfma_f32_16x16x32_bf16(a3, b3, acc[(m0_)+3][3], 0, 0, 0); \
  } while (0)
#define PH_RD8(kh_, buf_) do { \
    a0 = RD_A(0, kh_, buf_); a1 = RD_A(1, kh_, buf_); \
    a2 = RD_A(2, kh_, buf_); a3 = RD_A(3, kh_, buf_); \
    b0 = RD_B(0, kh_, buf_); b1 = RD_B(1, kh_, buf_); \
    b2 = RD_B(2, kh_, buf_); b3 = RD_B(3, kh_, buf_); } while (0)
#define PH_RD4(kh_, buf_) do { \
    a0 = RD_A(4, kh_, buf_); a1 = RD_A(5, kh_, buf_); \
    a2 = RD_A(6, kh_, buf_); a3 = RD_A(7, kh_, buf_); } while (0)
#define MFMA_BLK(m0_) do { \
    BARRIER(); \
    __builtin_amdgcn_s_setprio(1); \
    MFMA16(m0_); \
    __builtin_amdgcn_s_setprio(0); \
    BARRIER(); } while (0)

  // ---- prologue: tile0 kh0@0 kh1@32 + tile1 kh0@64 --------------------------
  STG_A(0, 0, 0); STG_B(0, 0, 0); STG_A(32, 1, 0); STG_B(32, 1, 0);
  STG_A(64, 0, 1); STG_B(64, 0, 1);
  VMCNT(4);
  BARRIER();

  bf16x8 a0, a1, a2, a3, b0, b1, b2, b3;

  // ---- steady state: branch-free, 2 K-tiles / iteration ----------------------
  for (int it = 0; it < NIT - 1; ++it) {
    // ===== tile t0 (buf 0) =====
    PH_RD8(0, 0); STG_A(96, 1, 1);              // A(t1,kh1) @ 64+32
    MFMA_BLK(0);
    PH_RD4(0, 0); STG_B(96, 1, 1); VMCNT(8);    // -> t0.kh1 ready
    MFMA_BLK(4);
    PH_RD8(1, 0); STG_A(128, 0, 0);             // A(t2,kh0) @ 128
    MFMA_BLK(0);
    PH_RD4(1, 0); STG_B(128, 0, 0); VMCNT(8);   // -> t1.kh0 ready
    MFMA_BLK(4);
    // ===== tile t1 (buf 1) =====
    PH_RD8(0, 1); STG_A(160, 1, 0);             // A(t2,kh1) @ 128+32
    MFMA_BLK(0);
    PH_RD4(0, 1); STG_B(160, 1, 0); VMCNT(8);   // -> t1.kh1 ready
    MFMA_BLK(4);
    PH_RD8(1, 1); STG_A(192, 0, 1);             // A(t3,kh0) @ 192
    MFMA_BLK(0);
    PH_RD4(1, 1); STG_B(192, 0, 1); VMCNT(8);   // -> t2.kh0 ready
    MFMA_BLK(4);
    aR0 += 128; aR1 += 128; bR0 += 128; bR1 += 128;
  }

  // ---- tail: last 2 tiles (t0 buf0 / t1 buf1); only A/B(t1,kh1)@96 to stage --
  PH_RD8(0, 0); STG_A(96, 1, 1);
  MFMA_BLK(0);
  PH_RD4(0, 0); STG_B(96, 1, 1); VMCNT(8);      // -> t0.kh1 ready
  MFMA_BLK(4);
  PH_RD8(1, 0);
  MFMA_BLK(0);
  PH_RD4(1, 0); VMCNT(4);                       // -> t1.kh0 ready
  MFMA_BLK(4);
  PH_RD8(0, 1);
  MFMA_BLK(0);
  PH_RD4(0, 1); VMCNT(0);                       // -> t1.kh1 ready
  MFMA_BLK(4);
  PH_RD8(1, 1);
  MFMA_BLK(0);
  PH_RD4(1, 1);
  MFMA_BLK(4);
#undef LDSA
#undef LDSB
#undef STG_A
#undef STG_B
#undef RD_A
#undef RD_B
#undef MFMA16
#undef PH_RD8
#undef PH_RD4
#undef MFMA_BLK
}

// staging source-column swizzle (involution with read side): g = (tid&3)^((tid>>3)&3)
__device__ __forceinline__ int stage_co() {
  const int tid = threadIdx.x;
  return (((tid & 3) ^ ((tid >> 3) & 3)) * 8);
}

// ---- stage A: kv^T, block-uniform split-store into k0T / vT ------------------
__global__ __launch_bounds__(512, 2) void k_gemm_kv(
    const uint16_t* __restrict__ W,    // wqkb 4096x2048
    const uint16_t* __restrict__ X,    // xb   8192x2048
    uint16_t* __restrict__ k0T,        // 2048x8192
    uint16_t* __restrict__ vT)         // 2048x8192
{
  const int tid = threadIdx.x;
  const int bm = blockIdx.y, bn = blockIdx.x;
  const int r0 = tid >> 2, co = stage_co();
  const uint16_t* aR0 = W + (size_t)(bm * 256 + r0) * 2048 + co;
  const uint16_t* aR1 = W + (size_t)(bm * 256 + 128 + r0) * 2048 + co;
  const uint16_t* bR0 = X + (size_t)(bn * 256 + r0) * 2048 + co;
  const uint16_t* bR1 = X + (size_t)(bn * 256 + 128 + r0) * 2048 + co;
  f32x4 acc[8][4];
#pragma unroll
  for (int i = 0; i < 8; ++i)
#pragma unroll
    for (int j = 0; j < 4; ++j) acc[i][j] = (f32x4){0.f, 0.f, 0.f, 0.f};
  gemm256_core(aR0, aR1, bR0, bR1, 2048, acc);
  const int w = tid >> 6, l = tid & 63;
  const int wm = (w >> 2) * 128, wn = (w & 3) * 64;
  const int cr = (l >> 4) * 4, cc = l & 15;
  uint16_t* Cb = (bm < 8) ? k0T : vT;
  const int rb = (bm & 7) * 256;
#pragma unroll
  for (int mi = 0; mi < 8; ++mi)
#pragma unroll
    for (int ni = 0; ni < 4; ++ni)
#pragma unroll
      for (int g = 0; g < 4; ++g) {
        int lr = rb + wm + mi * 16 + cr + g;
        int bt = bn * 256 + wn + ni * 16 + cc;
        Cb[(size_t)lr * 8192 + bt] = f2bf(acc[mi][ni][g]);
      }
}

// ---- generic batched A@B^T (both K-contig), scaled bf16 store ----------------
__global__ __launch_bounds__(512, 2) void k_gemm_bt(
    const uint16_t* __restrict__ A, int lda, long sA,
    const uint16_t* __restrict__ B, int ldb, long sB,
    uint16_t* __restrict__ C, int ldc, long sC,
    int K, float scale)
{
  const int z = blockIdx.z;
  A += (size_t)z * sA; B += (size_t)z * sB; C += (size_t)z * sC;
  const int tid = threadIdx.x;
  const int bm = blockIdx.y, bn = blockIdx.x;
  const int r0 = tid >> 2, co = stage_co();
  const uint16_t* aR0 = A + (size_t)(bm * 256 + r0) * lda + co;
  const uint16_t* aR1 = A + (size_t)(bm * 256 + 128 + r0) * lda + co;
  const uint16_t* bR0 = B + (size_t)(bn * 256 + r0) * ldb + co;
  const uint16_t* bR1 = B + (size_t)(bn * 256 + 128 + r0) * ldb + co;
  f32x4 acc[8][4];
#pragma unroll
  for (int i = 0; i < 8; ++i)
#pragma unroll
    for (int j = 0; j < 4; ++j) acc[i][j] = (f32x4){0.f, 0.f, 0.f, 0.f};
  gemm256_core(aR0, aR1, bR0, bR1, K, acc);
  const int w = tid >> 6, l = tid & 63;
  const int wm = (w >> 2) * 128, wn = (w & 3) * 64;
  const int cr = (l >> 4) * 4, cc = l & 15;
#pragma unroll
  for (int mi = 0; mi < 8; ++mi)
#pragma unroll
    for (int ni = 0; ni < 4; ++ni)
#pragma unroll
      for (int g = 0; g < 4; ++g) {
        int grow = bm * 256 + wm + mi * 16 + cr + g;
        int gcol = bn * 256 + wn + ni * 16 + cc;
        C[(size_t)grow * ldc + gcol] = f2bf(acc[mi][ni][g] * scale);
      }
}

// ---- stage D: permuted-A GEMM + fp32 bias/store into d_out -------------------
__device__ __forceinline__ size_t qrow_off(int rr) {
  // rr = b'*2048 + t' ; q row = (b_i, i), b_i=(t'>>4)&3, i=(t'&15)*128+b'*32+(t'>>6)
  int bp = rr >> 11, tp = rr & 2047;
  int bi = (tp >> 4) & 3;
  int i  = (tp & 15) * 128 + bp * 32 + (tp >> 6);
  return ((size_t)bi * 2048 + (size_t)i) * 2048;
}

__global__ __launch_bounds__(512, 2) void k_gemm_out(
    const uint16_t* __restrict__ Q,     // qb (4,2048,2048) bf16
    const uint16_t* __restrict__ W,     // wdb 2048x2048 bf16
    const float*    __restrict__ bias,  // b_dense fp32 (2048)
    float*          __restrict__ Out)   // d_out 8192x2048 fp32
{
  const int tid = threadIdx.x;
  const int bm = blockIdx.y, bn = blockIdx.x;
  const int r0 = tid >> 2, co = stage_co();
  const uint16_t* aR0 = Q + qrow_off(bm * 256 + r0) + co;
  const uint16_t* aR1 = Q + qrow_off(bm * 256 + 128 + r0) + co;
  const uint16_t* bR0 = W + (size_t)(bn * 256 + r0) * 2048 + co;
  const uint16_t* bR1 = W + (size_t)(bn * 256 + 128 + r0) * 2048 + co;
  f32x4 acc[8][4];
#pragma unroll
  for (int i = 0; i < 8; ++i)
#pragma unroll
    for (int j = 0; j < 4; ++j) acc[i][j] = (f32x4){0.f, 0.f, 0.f, 0.f};
  gemm256_core(aR0, aR1, bR0, bR1, 2048, acc);
  const int w = tid >> 6, l = tid & 63;
  const int wm = (w >> 2) * 128, wn = (w & 3) * 64;
  const int cr = (l >> 4) * 4, cc = l & 15;
#pragma unroll
  for (int mi = 0; mi < 8; ++mi)
#pragma unroll
    for (int ni = 0; ni < 4; ++ni)
#pragma unroll
      for (int g = 0; g < 4; ++g) {
        int grow = bm * 256 + wm + mi * 16 + cr + g;
        int gcol = bn * 256 + wn + ni * 16 + cc;
        Out[(size_t)grow * 2048 + gcol] = acc[mi][ni][g] + bias[gcol];
      }
}

// ---- transpose vT (2048x8192) -> Vn (8192x2048) ------------------------------
__global__ __launch_bounds__(256) void k_transpose(
    const uint16_t* __restrict__ src, uint16_t* __restrict__ dst)
{
  __shared__ uint16_t tile[64][65];
  const int tid = threadIdx.x;
  const int bx = blockIdx.x;
  const int by = blockIdx.y;
  const int cu = tid & 31, r0 = tid >> 5;
#pragma unroll
  for (int p = 0; p < 8; ++p) {
    int r = p * 8 + r0;
    uint32_t v = *reinterpret_cast<const uint32_t*>(
        &src[(size_t)(by * 64 + r) * 8192 + bx * 64 + cu * 2]);
    tile[r][cu * 2]     = (uint16_t)(v & 0xffffu);
    tile[r][cu * 2 + 1] = (uint16_t)(v >> 16);
  }
  __syncthreads();
#pragma unroll
  for (int p = 0; p < 8; ++p) {
    int r = p * 8 + r0;
    uint32_t lo = tile[cu * 2][r], hi = tile[cu * 2 + 1][r];
    *reinterpret_cast<uint32_t*>(
        &dst[(size_t)(bx * 64 + r) * 2048 + by * 64 + cu * 2]) = lo | (hi << 16);
  }
}

// ---- row softmax (bf16 in place), 1 block per row of 2048 --------------------
__global__ __launch_bounds__(256) void k_softmax(uint16_t* __restrict__ s)
{
  uint16_t* p = s + (size_t)blockIdx.x * 2048;
  const int tid = threadIdx.x;
  uint4 raw = reinterpret_cast<const uint4*>(p)[tid];
  uint32_t u[4] = {raw.x, raw.y, raw.z, raw.w};
  float x[8];
#pragma unroll
  for (int i = 0; i < 4; ++i) {
    x[2 * i]     = bf2f((uint16_t)(u[i] & 0xffffu));
    x[2 * i + 1] = bf2f((uint16_t)(u[i] >> 16));
  }
  float m = x[0];
#pragma unroll
  for (int i = 1; i < 8; ++i) m = fmaxf(m, x[i]);
#pragma unroll
  for (int o = 32; o; o >>= 1) m = fmaxf(m, __shfl_xor(m, o, 64));
  __shared__ float redm[4], reds[4];
  if ((tid & 63) == 0) redm[tid >> 6] = m;
  __syncthreads();
  m = fmaxf(fmaxf(redm[0], redm[1]), fmaxf(redm[2], redm[3]));
  float sum = 0.f;
#pragma unroll
  for (int i = 0; i < 8; ++i) { x[i] = __expf(x[i] - m); sum += x[i]; }
#pragma unroll
  for (int o = 32; o; o >>= 1) sum += __shfl_xor(sum, o, 64);
  if ((tid & 63) == 0) reds[tid >> 6] = sum;
  __syncthreads();
  sum = reds[0] + reds[1] + reds[2] + reds[3];
  float inv = 1.0f / sum;
  uint32_t ou[4];
#pragma unroll
  for (int i = 0; i < 4; ++i) {
    uint32_t lo = f2bf(x[2 * i] * inv);
    uint32_t hi = f2bf(x[2 * i + 1] * inv);
    ou[i] = lo | (hi << 16);
  }
  reinterpret_cast<uint4*>(p)[tid] = make_uint4(ou[0], ou[1], ou[2], ou[3]);
}

// ------------------------------------------------------------------------------
extern "C" void kernel_launch(void* const* d_in, const int* in_sizes, int n_in,
                              void* d_out, int out_size, void* d_ws, size_t ws_size,
                              hipStream_t stream) {
  const float* x       = (const float*)d_in[0];
  const float* w_qk    = (const float*)d_in[1];
  const float* w_dense = (const float*)d_in[2];
  const float* b_dense = (const float*)d_in[3];
  float* out = (float*)d_out;

  static int attr_done = 0;
  if (!attr_done) {
    (void)hipFuncSetAttribute(reinterpret_cast<const void*>(k_gemm_kv),
                              hipFuncAttributeMaxDynamicSharedMemorySize, 131072);
    (void)hipFuncSetAttribute(reinterpret_cast<const void*>(k_gemm_bt),
                              hipFuncAttributeMaxDynamicSharedMemorySize, 131072);
    (void)hipFuncSetAttribute(reinterpret_cast<const void*>(k_gemm_out),
                              hipFuncAttributeMaxDynamicSharedMemorySize, 131072);
    attr_done = 1;
  }

  const size_t NX = 4ull * 2048 * 2048;
  const size_t NW = 4096ull * 2048;
  const size_t ND = 2048ull * 2048;

  // d_ws layout (bf16): xb | wqkb | wdb | k0T | vT   (126 MB peak)
  uint16_t* xb   = (uint16_t*)d_ws;
  uint16_t* wqkb = xb + NX;
  uint16_t* wdb  = wqkb + NW;
  uint16_t* k0T  = wdb + ND;
  uint16_t* vT   = k0T + NX;
  uint16_t* qb   = xb;                    // alias: xb dead after stage A
  uint16_t* Vn   = (uint16_t*)d_out;      // d_out as scratch (dead before D)
  uint16_t* sb   = Vn + NX;

  const float scale = (float)(1.0 / sqrt(0.5 * 2048.0 * 2047.0));

  k_cast_all<<<dim3((NX4 + NW4 + ND4) / 256), 256, 0, stream>>>(x, w_qk, w_dense, xb);

  // A: kv^T  (M=4096 e, N=8192 bt, K=2048)
  k_gemm_kv<<<dim3(32, 16), 512, 131072, stream>>>(wqkb, xb, k0T, vT);
  // T: vT -> Vn
  k_transpose<<<dim3(128, 32), 256, 0, stream>>>(vT, Vn);
  // B: s = scale * k0T @ Vn^T
  k_gemm_bt<<<dim3(8, 8, 4), 512, 131072, stream>>>(
      k0T, 8192, 2048L, Vn, 2048, 2048L * 2048L, sb, 2048, 2048L * 2048L, 2048, scale);
  // S: softmax rows
  k_softmax<<<dim3(8192), 256, 0, stream>>>(sb);
  // C: q = a @ vT^T
  k_gemm_bt<<<dim3(8, 8, 4), 512, 131072, stream>>>(
      sb, 2048, 2048L * 2048L, vT, 8192, 2048L, qb, 2048, 2048L * 2048L, 2048, 1.0f);
  // D: out = perm(q) @ w_dense^T + bias -> fp32
  k_gemm_out<<<dim3(8, 32), 512, 131072, stream>>>(qb, wdb, b_dense, out);
}

// Round 4
// 478.073 us; speedup vs baseline: 1.0338x; 1.0338x over previous
//
#include <hip/hip_runtime.h>
#include <stdint.h>
#include <math.h>

// B=4, T=2048, D=2048, HEADS=16.  Inputs/outputs fp32; internal bf16 MFMA.
//
// Pipeline: cast -> A: kv^T -> T: transpose -> B: scores -> S: softmax ->
//           C: q = a@vT^T -> D: perm(q)@w_dense^T + bias.
//
// GEMM core: 256x256 8-phase schedule (T2+T3+T4+T5), UNROLLED 2 K-tiles/iter.
//
// ROUND-4 CHANGE (single change): barrier/waitcnt asm previously carried
// ":::memory" clobbers.  global_load_lds WRITES LDS (memory), so a memory-
// clobber asm is a potential reader -> SIInsertWaitcnts conservatively drains
// vmcnt(0)/lgkmcnt(0) before EVERY fence, i.e. before every s_barrier: the
// exact m97 drain stall, nullifying the counted-vmcnt design.  Now: bare
// s_barrier + bare waitcnt asm, with __builtin_amdgcn_sched_barrier(0) on each
// side of the barrier to pin compile-time motion (ds_reads must not hoist
// above the data-ready barrier).  Zero runtime cost.  Ledger unchanged from
// the round-3 version that passed bit-exact.
//
//  - 512 thr = 8 waves (2M x 4N), per-wave output 128x64 (acc[8][4] f32x4).
//  - BK=64 in two kh-halves of 32; LDS = 2dbuf x {A,B} x [2kh][256r x 32c] bf16
//    = 128 KiB dynamic.  Region granularity = (op, kh) half (16 KiB).
//  - Staging: global_load_lds width=16, LINEAR LDS dest; global source chunk
//    g = (tid&3)^((tid>>3)&3) (involution with read-side XOR) -> 0 bank
//    conflicts (verified round 1).
//  - Steady-state ledger (per iter, tiles t0=2it buf0 / t1=2it+1 buf1),
//    full K-offsets relative to iter base (tile t0 at offset 0):
//      t0P1 stg@96  A(t1,kh1)   t0P2 stg@96  B(t1,kh1) vmcnt(8)->t0.kh1 ready
//      t0P3 stg@128 A(t2,kh0)   t0P4 stg@128 B(t2,kh0) vmcnt(8)->t1.kh0 ready
//      t1P1 stg@160 A(t2,kh1)   t1P2 stg@160 B(t2,kh1) vmcnt(8)->t1.kh1 ready
//      t1P3 stg@192 A(t3,kh0)   t1P4 stg@192 B(t3,kh0) vmcnt(8)->t2.kh0 ready
//    Every stg targets a region whose last reader finished >=1 barrier earlier.
//    Tail (last 2 tiles): stg only A/B@96 (t1,kh1); waits 8 -> 4 -> 0.
//    Prologue: t0 kh0@0, kh1@32 + t1 kh0@64; vmcnt(4).  K % 128 == 0.
//  - Grids: gridDim.x % 8 == 0 with bn fastest => B-operand panels already
//    XCD-affine under default round-robin dispatch; no swizzle applied.

typedef __bf16 bf16x8 __attribute__((ext_vector_type(8)));
typedef float  f32x4  __attribute__((ext_vector_type(4)));

typedef __attribute__((address_space(3))) uint32_t lds_u32_t;
typedef __attribute__((address_space(1))) const uint32_t glb_u32_t;

__device__ __forceinline__ float bf2f(uint16_t u) {
  union { uint32_t i; float f; } c; c.i = ((uint32_t)u) << 16; return c.f;
}
__device__ __forceinline__ uint16_t f2bf(float f) {
  union { float f; uint32_t i; } c; c.f = f;
  uint32_t i = c.i;
  return (uint16_t)((i + 0x7fffu + ((i >> 16) & 1u)) >> 16);  // RNE
}

__device__ __forceinline__ void glds16(const uint16_t* g, const char* l) {
  __builtin_amdgcn_global_load_lds((glb_u32_t*)g, (lds_u32_t*)l, 16, 0, 0);
}

#define SCHED0() __builtin_amdgcn_sched_barrier(0)
#define BARRIER() do { SCHED0(); __builtin_amdgcn_s_barrier(); SCHED0(); } while (0)
#define VMCNT(n_) asm volatile("s_waitcnt vmcnt(" #n_ ")")

// ---- fused fp32 -> bf16 cast over x|w_qk|w_dense -----------------------------
#define NX4 4194304u
#define NW4 2097152u
#define ND4 1048576u
__global__ __launch_bounds__(256) void k_cast_all(
    const float* __restrict__ x, const float* __restrict__ wqk,
    const float* __restrict__ wd, uint16_t* __restrict__ dst) {
  uint32_t i = blockIdx.x * 256 + threadIdx.x;
  float4 v;
  if (i < NX4)            v = reinterpret_cast<const float4*>(x)[i];
  else if (i < NX4 + NW4) v = reinterpret_cast<const float4*>(wqk)[i - NX4];
  else                    v = reinterpret_cast<const float4*>(wd)[i - NX4 - NW4];
  ushort4 o;
  o.x = f2bf(v.x); o.y = f2bf(v.y); o.z = f2bf(v.z); o.w = f2bf(v.w);
  reinterpret_cast<ushort4*>(dst)[i] = o;
}

// ---- 256x256 8-phase GEMM core, 2 K-tiles per iteration ---------------------
// aR0/aR1/bR0/bR1: per-thread staging sources, rows (tid>>2) and (tid>>2)+128
// of the 256-row tile, at k=0, swizzled chunk offset already added.
__device__ __forceinline__ void gemm256_core(
    const uint16_t* aR0, const uint16_t* aR1,
    const uint16_t* bR0, const uint16_t* bR1,
    int K, f32x4 acc[8][4])
{
  extern __shared__ uint4 smem_u4[];
  char* smem = (char*)smem_u4;
  const int tid = threadIdx.x;
  const int w = tid >> 6, l = tid & 63;
  const int wm = (w >> 2) * 128, wn = (w & 3) * 64;
  const int frow = l & 15, fkc = l >> 4;
  // read-side chunk swizzle: chunk' = fkc ^ ((frow>>1)&3)  (fixed per lane)
  const uint32_t chunk = (uint32_t)((fkc ^ ((frow >> 1) & 3)) * 16);
  const uint32_t aBase = (uint32_t)(wm + frow) * 64 + chunk;           // +mi*1024 +kh*16384 +buf*32768
  const uint32_t bBase = 65536u + (uint32_t)(wn + frow) * 64 + chunk;  // +ni*1024 +kh*16384 +buf*32768
  char* lW = smem + (uint32_t)w * 1024u;   // per-wave staging dest base
  const int NIT = K >> 7;                  // iterations of 2 K-tiles; K % 128 == 0

#define LDSA(kh_, buf_, half_) (lW + ((buf_) * 32768u + (kh_) * 16384u + (half_) * 8192u))
#define LDSB(kh_, buf_, half_) (lW + (65536u + (buf_) * 32768u + (kh_) * 16384u + (half_) * 8192u))
// off_ is the FULL K-offset in elements (tile*64 + kh*32); kh_ selects the LDS
// destination region only.
#define STG_A(off_, kh_, buf_) do { \
    glds16(aR0 + (off_), LDSA(kh_, buf_, 0)); \
    glds16(aR1 + (off_), LDSA(kh_, buf_, 1)); } while (0)
#define STG_B(off_, kh_, buf_) do { \
    glds16(bR0 + (off_), LDSB(kh_, buf_, 0)); \
    glds16(bR1 + (off_), LDSB(kh_, buf_, 1)); } while (0)
#define RD_A(mi_, kh_, buf_) \
    (*reinterpret_cast<const bf16x8*>(smem + (aBase + (mi_) * 1024u + (kh_) * 16384u + (buf_) * 32768u)))
#define RD_B(ni_, kh_, buf_) \
    (*reinterpret_cast<const bf16x8*>(smem + (bBase + (ni_) * 1024u + (kh_) * 16384u + (buf_) * 32768u)))
#define MFMA16(m0_) do { \
    acc[(m0_)+0][0] = __builtin_amdgcn_mfma_f32_16x16x32_bf16(a0, b0, acc[(m0_)+0][0], 0, 0, 0); \
    acc[(m0_)+1][0] = __builtin_amdgcn_mfma_f32_16x16x32_bf16(a1, b0, acc[(m0_)+1][0], 0, 0, 0); \
    acc[(m0_)+2][0] = __builtin_amdgcn_mfma_f32_16x16x32_bf16(a2, b0, acc[(m0_)+2][0], 0, 0, 0); \
    acc[(m0_)+3][0] = __builtin_amdgcn_mfma_f32_16x16x32_bf16(a3, b0, acc[(m0_)+3][0], 0, 0, 0); \
    acc[(m0_)+0][1] = __builtin_amdgcn_mfma_f32_16x16x32_bf16(a0, b1, acc[(m0_)+0][1], 0, 0, 0); \
    acc[(m0_)+1][1] = __builtin_amdgcn_mfma_f32_16x16x32_bf16(a1, b1, acc[(m0_)+1][1], 0, 0, 0); \
    acc[(m0_)+2][1] = __builtin_amdgcn_mfma_f32_16x16x32_bf16(a2, b1, acc[(m0_)+2][1], 0, 0, 0); \
    acc[(m0_)+3][1] = __builtin_amdgcn_mfma_f32_16x16x32_bf16(a3, b1, acc[(m0_)+3][1], 0, 0, 0); \
    acc[(m0_)+0][2] = __builtin_amdgcn_mfma_f32_16x16x32_bf16(a0, b2, acc[(m0_)+0][2], 0, 0, 0); \
    acc[(m0_)+1][2] = __builtin_amdgcn_mfma_f32_16x16x32_bf16(a1, b2, acc[(m0_)+1][2], 0, 0, 0); \
    acc[(m0_)+2][2] = __builtin_amdgcn_mfma_f32_16x16x32_bf16(a2, b2, acc[(m0_)+2][2], 0, 0, 0); \
    acc[(m0_)+3][2] = __builtin_amdgcn_mfma_f32_16x16x32_bf16(a3, b2, acc[(m0_)+3][2], 0, 0, 0); \
    acc[(m0_)+0][3] = __builtin_amdgcn_mfma_f32_16x16x32_bf16(a0, b3, acc[(m0_)+0][3], 0, 0, 0); \
    acc[(m0_)+1][3] = __builtin_amdgcn_mfma_f32_16x16x32_bf16(a1, b3, acc[(m0_)+1][3], 0, 0, 0); \
    acc[(m0_)+2][3] = __builtin_amdgcn_mfma_f32_16x16x32_bf16(a2, b3, acc[(m0_)+2][3], 0, 0, 0); \
    acc[(m0_)+3][3] = __builtin_amdgcn_mfma_f32_16x16x32_bf16(a3, b3, acc[(m0_)+3][3], 0, 0, 0); \
  } while (0)
#define PH_RD8(kh_, buf_) do { \
    a0 = RD_A(0, kh_, buf_); a1 = RD_A(1, kh_, buf_); \
    a2 = RD_A(2, kh_, buf_); a3 = RD_A(3, kh_, buf_); \
    b0 = RD_B(0, kh_, buf_); b1 = RD_B(1, kh_, buf_); \
    b2 = RD_B(2, kh_, buf_); b3 = RD_B(3, kh_, buf_); } while (0)
#define PH_RD4(kh_, buf_) do { \
    a0 = RD_A(4, kh_, buf_); a1 = RD_A(5, kh_, buf_); \
    a2 = RD_A(6, kh_, buf_); a3 = RD_A(7, kh_, buf_); } while (0)
#define MFMA_BLK(m0_) do { \
    BARRIER(); \
    __builtin_amdgcn_s_setprio(1); \
    MFMA16(m0_); \
    __builtin_amdgcn_s_setprio(0); \
    BARRIER(); } while (0)

  // ---- prologue: tile0 kh0@0 kh1@32 + tile1 kh0@64 --------------------------
  STG_A(0, 0, 0); STG_B(0, 0, 0); STG_A(32, 1, 0); STG_B(32, 1, 0);
  STG_A(64, 0, 1); STG_B(64, 0, 1);
  VMCNT(4);
  BARRIER();

  bf16x8 a0, a1, a2, a3, b0, b1, b2, b3;

  // ---- steady state: branch-free, 2 K-tiles / iteration ----------------------
  for (int it = 0; it < NIT - 1; ++it) {
    // ===== tile t0 (buf 0) =====
    PH_RD8(0, 0); STG_A(96, 1, 1);              // A(t1,kh1) @ 64+32
    MFMA_BLK(0);
    PH_RD4(0, 0); STG_B(96, 1, 1); VMCNT(8);    // -> t0.kh1 ready
    MFMA_BLK(4);
    PH_RD8(1, 0); STG_A(128, 0, 0);             // A(t2,kh0) @ 128
    MFMA_BLK(0);
    PH_RD4(1, 0); STG_B(128, 0, 0); VMCNT(8);   // -> t1.kh0 ready
    MFMA_BLK(4);
    // ===== tile t1 (buf 1) =====
    PH_RD8(0, 1); STG_A(160, 1, 0);             // A(t2,kh1) @ 128+32
    MFMA_BLK(0);
    PH_RD4(0, 1); STG_B(160, 1, 0); VMCNT(8);   // -> t1.kh1 ready
    MFMA_BLK(4);
    PH_RD8(1, 1); STG_A(192, 0, 1);             // A(t3,kh0) @ 192
    MFMA_BLK(0);
    PH_RD4(1, 1); STG_B(192, 0, 1); VMCNT(8);   // -> t2.kh0 ready
    MFMA_BLK(4);
    aR0 += 128; aR1 += 128; bR0 += 128; bR1 += 128;
  }

  // ---- tail: last 2 tiles (t0 buf0 / t1 buf1); only A/B(t1,kh1)@96 to stage --
  PH_RD8(0, 0); STG_A(96, 1, 1);
  MFMA_BLK(0);
  PH_RD4(0, 0); STG_B(96, 1, 1); VMCNT(8);      // -> t0.kh1 ready
  MFMA_BLK(4);
  PH_RD8(1, 0);
  MFMA_BLK(0);
  PH_RD4(1, 0); VMCNT(4);                       // -> t1.kh0 ready
  MFMA_BLK(4);
  PH_RD8(0, 1);
  MFMA_BLK(0);
  PH_RD4(0, 1); VMCNT(0);                       // -> t1.kh1 ready
  MFMA_BLK(4);
  PH_RD8(1, 1);
  MFMA_BLK(0);
  PH_RD4(1, 1);
  MFMA_BLK(4);
#undef LDSA
#undef LDSB
#undef STG_A
#undef STG_B
#undef RD_A
#undef RD_B
#undef MFMA16
#undef PH_RD8
#undef PH_RD4
#undef MFMA_BLK
}

// staging source-column swizzle (involution with read side): g = (tid&3)^((tid>>3)&3)
__device__ __forceinline__ int stage_co() {
  const int tid = threadIdx.x;
  return (((tid & 3) ^ ((tid >> 3) & 3)) * 8);
}

// ---- stage A: kv^T, block-uniform split-store into k0T / vT ------------------
__global__ __launch_bounds__(512, 2) void k_gemm_kv(
    const uint16_t* __restrict__ W,    // wqkb 4096x2048
    const uint16_t* __restrict__ X,    // xb   8192x2048
    uint16_t* __restrict__ k0T,        // 2048x8192
    uint16_t* __restrict__ vT)         // 2048x8192
{
  const int tid = threadIdx.x;
  const int bm = blockIdx.y, bn = blockIdx.x;
  const int r0 = tid >> 2, co = stage_co();
  const uint16_t* aR0 = W + (size_t)(bm * 256 + r0) * 2048 + co;
  const uint16_t* aR1 = W + (size_t)(bm * 256 + 128 + r0) * 2048 + co;
  const uint16_t* bR0 = X + (size_t)(bn * 256 + r0) * 2048 + co;
  const uint16_t* bR1 = X + (size_t)(bn * 256 + 128 + r0) * 2048 + co;
  f32x4 acc[8][4];
#pragma unroll
  for (int i = 0; i < 8; ++i)
#pragma unroll
    for (int j = 0; j < 4; ++j) acc[i][j] = (f32x4){0.f, 0.f, 0.f, 0.f};
  gemm256_core(aR0, aR1, bR0, bR1, 2048, acc);
  const int w = tid >> 6, l = tid & 63;
  const int wm = (w >> 2) * 128, wn = (w & 3) * 64;
  const int cr = (l >> 4) * 4, cc = l & 15;
  uint16_t* Cb = (bm < 8) ? k0T : vT;
  const int rb = (bm & 7) * 256;
#pragma unroll
  for (int mi = 0; mi < 8; ++mi)
#pragma unroll
    for (int ni = 0; ni < 4; ++ni)
#pragma unroll
      for (int g = 0; g < 4; ++g) {
        int lr = rb + wm + mi * 16 + cr + g;
        int bt = bn * 256 + wn + ni * 16 + cc;
        Cb[(size_t)lr * 8192 + bt] = f2bf(acc[mi][ni][g]);
      }
}

// ---- generic batched A@B^T (both K-contig), scaled bf16 store ----------------
__global__ __launch_bounds__(512, 2) void k_gemm_bt(
    const uint16_t* __restrict__ A, int lda, long sA,
    const uint16_t* __restrict__ B, int ldb, long sB,
    uint16_t* __restrict__ C, int ldc, long sC,
    int K, float scale)
{
  const int z = blockIdx.z;
  A += (size_t)z * sA; B += (size_t)z * sB; C += (size_t)z * sC;
  const int tid = threadIdx.x;
  const int bm = blockIdx.y, bn = blockIdx.x;
  const int r0 = tid >> 2, co = stage_co();
  const uint16_t* aR0 = A + (size_t)(bm * 256 + r0) * lda + co;
  const uint16_t* aR1 = A + (size_t)(bm * 256 + 128 + r0) * lda + co;
  const uint16_t* bR0 = B + (size_t)(bn * 256 + r0) * ldb + co;
  const uint16_t* bR1 = B + (size_t)(bn * 256 + 128 + r0) * ldb + co;
  f32x4 acc[8][4];
#pragma unroll
  for (int i = 0; i < 8; ++i)
#pragma unroll
    for (int j = 0; j < 4; ++j) acc[i][j] = (f32x4){0.f, 0.f, 0.f, 0.f};
  gemm256_core(aR0, aR1, bR0, bR1, K, acc);
  const int w = tid >> 6, l = tid & 63;
  const int wm = (w >> 2) * 128, wn = (w & 3) * 64;
  const int cr = (l >> 4) * 4, cc = l & 15;
#pragma unroll
  for (int mi = 0; mi < 8; ++mi)
#pragma unroll
    for (int ni = 0; ni < 4; ++ni)
#pragma unroll
      for (int g = 0; g < 4; ++g) {
        int grow = bm * 256 + wm + mi * 16 + cr + g;
        int gcol = bn * 256 + wn + ni * 16 + cc;
        C[(size_t)grow * ldc + gcol] = f2bf(acc[mi][ni][g] * scale);
      }
}

// ---- stage D: permuted-A GEMM + fp32 bias/store into d_out -------------------
__device__ __forceinline__ size_t qrow_off(int rr) {
  // rr = b'*2048 + t' ; q row = (b_i, i), b_i=(t'>>4)&3, i=(t'&15)*128+b'*32+(t'>>6)
  int bp = rr >> 11, tp = rr & 2047;
  int bi = (tp >> 4) & 3;
  int i  = (tp & 15) * 128 + bp * 32 + (tp >> 6);
  return ((size_t)bi * 2048 + (size_t)i) * 2048;
}

__global__ __launch_bounds__(512, 2) void k_gemm_out(
    const uint16_t* __restrict__ Q,     // qb (4,2048,2048) bf16
    const uint16_t* __restrict__ W,     // wdb 2048x2048 bf16
    const float*    __restrict__ bias,  // b_dense fp32 (2048)
    float*          __restrict__ Out)   // d_out 8192x2048 fp32
{
  const int tid = threadIdx.x;
  const int bm = blockIdx.y, bn = blockIdx.x;
  const int r0 = tid >> 2, co = stage_co();
  const uint16_t* aR0 = Q + qrow_off(bm * 256 + r0) + co;
  const uint16_t* aR1 = Q + qrow_off(bm * 256 + 128 + r0) + co;
  const uint16_t* bR0 = W + (size_t)(bn * 256 + r0) * 2048 + co;
  const uint16_t* bR1 = W + (size_t)(bn * 256 + 128 + r0) * 2048 + co;
  f32x4 acc[8][4];
#pragma unroll
  for (int i = 0; i < 8; ++i)
#pragma unroll
    for (int j = 0; j < 4; ++j) acc[i][j] = (f32x4){0.f, 0.f, 0.f, 0.f};
  gemm256_core(aR0, aR1, bR0, bR1, 2048, acc);
  const int w = tid >> 6, l = tid & 63;
  const int wm = (w >> 2) * 128, wn = (w & 3) * 64;
  const int cr = (l >> 4) * 4, cc = l & 15;
#pragma unroll
  for (int mi = 0; mi < 8; ++mi)
#pragma unroll
    for (int ni = 0; ni < 4; ++ni)
#pragma unroll
      for (int g = 0; g < 4; ++g) {
        int grow = bm * 256 + wm + mi * 16 + cr + g;
        int gcol = bn * 256 + wn + ni * 16 + cc;
        Out[(size_t)grow * 2048 + gcol] = acc[mi][ni][g] + bias[gcol];
      }
}

// ---- transpose vT (2048x8192) -> Vn (8192x2048) ------------------------------
__global__ __launch_bounds__(256) void k_transpose(
    const uint16_t* __restrict__ src, uint16_t* __restrict__ dst)
{
  __shared__ uint16_t tile[64][65];
  const int tid = threadIdx.x;
  const int bx = blockIdx.x;
  const int by = blockIdx.y;
  const int cu = tid & 31, r0 = tid >> 5;
#pragma unroll
  for (int p = 0; p < 8; ++p) {
    int r = p * 8 + r0;
    uint32_t v = *reinterpret_cast<const uint32_t*>(
        &src[(size_t)(by * 64 + r) * 8192 + bx * 64 + cu * 2]);
    tile[r][cu * 2]     = (uint16_t)(v & 0xffffu);
    tile[r][cu * 2 + 1] = (uint16_t)(v >> 16);
  }
  __syncthreads();
#pragma unroll
  for (int p = 0; p < 8; ++p) {
    int r = p * 8 + r0;
    uint32_t lo = tile[cu * 2][r], hi = tile[cu * 2 + 1][r];
    *reinterpret_cast<uint32_t*>(
        &dst[(size_t)(bx * 64 + r) * 2048 + by * 64 + cu * 2]) = lo | (hi << 16);
  }
}

// ---- row softmax (bf16 in place), 1 block per row of 2048 --------------------
__global__ __launch_bounds__(256) void k_softmax(uint16_t* __restrict__ s)
{
  uint16_t* p = s + (size_t)blockIdx.x * 2048;
  const int tid = threadIdx.x;
  uint4 raw = reinterpret_cast<const uint4*>(p)[tid];
  uint32_t u[4] = {raw.x, raw.y, raw.z, raw.w};
  float x[8];
#pragma unroll
  for (int i = 0; i < 4; ++i) {
    x[2 * i]     = bf2f((uint16_t)(u[i] & 0xffffu));
    x[2 * i + 1] = bf2f((uint16_t)(u[i] >> 16));
  }
  float m = x[0];
#pragma unroll
  for (int i = 1; i < 8; ++i) m = fmaxf(m, x[i]);
#pragma unroll
  for (int o = 32; o; o >>= 1) m = fmaxf(m, __shfl_xor(m, o, 64));
  __shared__ float redm[4], reds[4];
  if ((tid & 63) == 0) redm[tid >> 6] = m;
  __syncthreads();
  m = fmaxf(fmaxf(redm[0], redm[1]), fmaxf(redm[2], redm[3]));
  float sum = 0.f;
#pragma unroll
  for (int i = 0; i < 8; ++i) { x[i] = __expf(x[i] - m); sum += x[i]; }
#pragma unroll
  for (int o = 32; o; o >>= 1) sum += __shfl_xor(sum, o, 64);
  if ((tid & 63) == 0) reds[tid >> 6] = sum;
  __syncthreads();
  sum = reds[0] + reds[1] + reds[2] + reds[3];
  float inv = 1.0f / sum;
  uint32_t ou[4];
#pragma unroll
  for (int i = 0; i < 4; ++i) {
    uint32_t lo = f2bf(x[2 * i] * inv);
    uint32_t hi = f2bf(x[2 * i + 1] * inv);
    ou[i] = lo | (hi << 16);
  }
  reinterpret_cast<uint4*>(p)[tid] = make_uint4(ou[0], ou[1], ou[2], ou[3]);
}

// ------------------------------------------------------------------------------
extern "C" void kernel_launch(void* const* d_in, const int* in_sizes, int n_in,
                              void* d_out, int out_size, void* d_ws, size_t ws_size,
                              hipStream_t stream) {
  const float* x       = (const float*)d_in[0];
  const float* w_qk    = (const float*)d_in[1];
  const float* w_dense = (const float*)d_in[2];
  const float* b_dense = (const float*)d_in[3];
  float* out = (float*)d_out;

  static int attr_done = 0;
  if (!attr_done) {
    (void)hipFuncSetAttribute(reinterpret_cast<const void*>(k_gemm_kv),
                              hipFuncAttributeMaxDynamicSharedMemorySize, 131072);
    (void)hipFuncSetAttribute(reinterpret_cast<const void*>(k_gemm_bt),
                              hipFuncAttributeMaxDynamicSharedMemorySize, 131072);
    (void)hipFuncSetAttribute(reinterpret_cast<const void*>(k_gemm_out),
                              hipFuncAttributeMaxDynamicSharedMemorySize, 131072);
    attr_done = 1;
  }

  const size_t NX = 4ull * 2048 * 2048;
  const size_t NW = 4096ull * 2048;
  const size_t ND = 2048ull * 2048;

  // d_ws layout (bf16): xb | wqkb | wdb | k0T | vT   (126 MB peak)
  uint16_t* xb   = (uint16_t*)d_ws;
  uint16_t* wqkb = xb + NX;
  uint16_t* wdb  = wqkb + NW;
  uint16_t* k0T  = wdb + ND;
  uint16_t* vT   = k0T + NX;
  uint16_t* qb   = xb;                    // alias: xb dead after stage A
  uint16_t* Vn   = (uint16_t*)d_out;      // d_out as scratch (dead before D)
  uint16_t* sb   = Vn + NX;

  const float scale = (float)(1.0 / sqrt(0.5 * 2048.0 * 2047.0));

  k_cast_all<<<dim3((NX4 + NW4 + ND4) / 256), 256, 0, stream>>>(x, w_qk, w_dense, xb);

  // A: kv^T  (M=4096 e, N=8192 bt, K=2048)
  k_gemm_kv<<<dim3(32, 16), 512, 131072, stream>>>(wqkb, xb, k0T, vT);
  // T: vT -> Vn
  k_transpose<<<dim3(128, 32), 256, 0, stream>>>(vT, Vn);
  // B: s = scale * k0T @ Vn^T
  k_gemm_bt<<<dim3(8, 8, 4), 512, 131072, stream>>>(
      k0T, 8192, 2048L, Vn, 2048, 2048L * 2048L, sb, 2048, 2048L * 2048L, 2048, scale);
  // S: softmax rows
  k_softmax<<<dim3(8192), 256, 0, stream>>>(sb);
  // C: q = a @ vT^T
  k_gemm_bt<<<dim3(8, 8, 4), 512, 131072, stream>>>(
      sb, 2048, 2048L * 2048L, vT, 8192, 2048L, qb, 2048, 2048L * 2048L, 2048, 1.0f);
  // D: out = perm(q) @ w_dense^T + bias -> fp32
  k_gemm_out<<<dim3(8, 32), 512, 131072, stream>>>(qb, wdb, b_dense, out);
}

// Round 5
// 468.867 us; speedup vs baseline: 1.0541x; 1.0196x over previous
//
#include <hip/hip_runtime.h>
#include <stdint.h>
#include <math.h>

// B=4, T=2048, D=2048, HEADS=16.  Inputs/outputs fp32; internal bf16 MFMA.
//
// Pipeline: cast -> A: kv^T -> T: transpose -> B: scores -> S: softmax ->
//           C: q = a@vT^T -> D: perm(q)@w_dense^T + bias.
//
// GEMM core: 256x256 8-phase schedule, 2 K-tiles/iter, ONE barrier per phase.
//
// ROUND-5 CHANGE (single change): drop the post-MFMA barrier.  Old phase =
// [RD,STG,VM] B1 [MFMA] B2 (8 barriers/K-tile, sched-fenced on both sides of
// each barrier -> ds_read/stage segment can never overlap MFMA: lockstep).
// New phase = [RD(p),STG(p),VM(p)?] BAR(p) [MFMA(p)] -> 4 barriers/K-tile and
// the region between barriers is [MFMA(p), RD(p+1), STG(p+1)] with no internal
// fences: compiler may interleave next-phase ds_reads / load-issues into the
// MFMA cluster, and waves overlap each other's phases.
//
// One-barrier ledger proof (iter-relative load indices; prologue=S1..S12,
// P1:S13,S14=A96  P2:S15,S16=B96  P3:S17,S18=A128  P4:S19,S20=B128
// P5:S21,S22=A160 P6:S23,S24=B160 P7:S25,S26=A192  P8:S27,S28=B192):
//  data-ready (load -> issuer's vmcnt -> barrier -> any wave's read):
//   P1.RD8 buf0.kh0 <- prev P8 VM(8) [newest 8 = prevS21..28 excl S17..20? no:
//     at prev-P8.VM outstanding 8 = prevS21..S28 -> prevS17..20 landed] + BAR8.
//   P3.RD8 buf0.kh1 <- P2.VM(8) [newest 8 = prevS25..28,S13..16 -> prevS21..24
//     landed] + BAR2.   P5 buf1.kh0 <- P4.VM(8) [newest = S13..20] + BAR4.
//   P7 buf1.kh1 <- P6.VM(8) [newest = S17..24 -> S13..16 landed] + BAR6.
//  anti-dep (STG >= 1 barrier after last reader of its region):
//   S13/14 (buf1.A.kh1, last read prev-P7 < prev-BAR7) issued after prev-BAR8.
//   S15/16 (buf1.B.kh1, last read prev-P7) after prev-BAR8+BAR1.
//   S17/18 (buf0.A.kh0, last read P2.RD4 < BAR2) after BAR2.
//   S19/20 (buf0.B.kh0, last read P1.RD8 < BAR1) after BAR3.
//   S21/22 (buf0.A.kh1, last read P4.RD4 < BAR4) after BAR4.
//   S23/24 (buf0.B.kh1, last read P3.RD8 < BAR3) after BAR5.
//   S25/26 (buf1.A.kh0, last read P6.RD4 < BAR6) after BAR6.
//   S27/28 (buf1.B.kh0, last read P5.RD8 < BAR5) after BAR7.   All hold.
//  tail: stages only A/B@96; waits 8 -> 4 -> 0 (same proof, truncated).
//
//  - 512 thr = 8 waves (2M x 4N), per-wave output 128x64 (acc[8][4] f32x4).
//  - BK=64 in two kh-halves of 32; LDS = 2dbuf x {A,B} x [2kh][256r x 32c] bf16
//    = 128 KiB dynamic.  Region granularity = (op, kh) half (16 KiB).
//  - Staging: global_load_lds width=16, LINEAR LDS dest; global source chunk
//    g = (tid&3)^((tid>>3)&3) (involution with read-side XOR) -> 0 bank
//    conflicts (verified).
//  - Grids: gridDim.x % 8 == 0 with bn fastest => B-operand panels already
//    XCD-affine under default round-robin dispatch; no swizzle applied.

typedef __bf16 bf16x8 __attribute__((ext_vector_type(8)));
typedef float  f32x4  __attribute__((ext_vector_type(4)));

typedef __attribute__((address_space(3))) uint32_t lds_u32_t;
typedef __attribute__((address_space(1))) const uint32_t glb_u32_t;

__device__ __forceinline__ float bf2f(uint16_t u) {
  union { uint32_t i; float f; } c; c.i = ((uint32_t)u) << 16; return c.f;
}
__device__ __forceinline__ uint16_t f2bf(float f) {
  union { float f; uint32_t i; } c; c.f = f;
  uint32_t i = c.i;
  return (uint16_t)((i + 0x7fffu + ((i >> 16) & 1u)) >> 16);  // RNE
}

__device__ __forceinline__ void glds16(const uint16_t* g, const char* l) {
  __builtin_amdgcn_global_load_lds((glb_u32_t*)g, (lds_u32_t*)l, 16, 0, 0);
}

#define SCHED0() __builtin_amdgcn_sched_barrier(0)
#define BARRIER() do { SCHED0(); __builtin_amdgcn_s_barrier(); SCHED0(); } while (0)
#define VMCNT(n_) asm volatile("s_waitcnt vmcnt(" #n_ ")")

// ---- fused fp32 -> bf16 cast over x|w_qk|w_dense -----------------------------
#define NX4 4194304u
#define NW4 2097152u
#define ND4 1048576u
__global__ __launch_bounds__(256) void k_cast_all(
    const float* __restrict__ x, const float* __restrict__ wqk,
    const float* __restrict__ wd, uint16_t* __restrict__ dst) {
  uint32_t i = blockIdx.x * 256 + threadIdx.x;
  float4 v;
  if (i < NX4)            v = reinterpret_cast<const float4*>(x)[i];
  else if (i < NX4 + NW4) v = reinterpret_cast<const float4*>(wqk)[i - NX4];
  else                    v = reinterpret_cast<const float4*>(wd)[i - NX4 - NW4];
  ushort4 o;
  o.x = f2bf(v.x); o.y = f2bf(v.y); o.z = f2bf(v.z); o.w = f2bf(v.w);
  reinterpret_cast<ushort4*>(dst)[i] = o;
}

// ---- 256x256 8-phase GEMM core, 2 K-tiles per iteration ---------------------
// aR0/aR1/bR0/bR1: per-thread staging sources, rows (tid>>2) and (tid>>2)+128
// of the 256-row tile, at k=0, swizzled chunk offset already added.
__device__ __forceinline__ void gemm256_core(
    const uint16_t* aR0, const uint16_t* aR1,
    const uint16_t* bR0, const uint16_t* bR1,
    int K, f32x4 acc[8][4])
{
  extern __shared__ uint4 smem_u4[];
  char* smem = (char*)smem_u4;
  const int tid = threadIdx.x;
  const int w = tid >> 6, l = tid & 63;
  const int wm = (w >> 2) * 128, wn = (w & 3) * 64;
  const int frow = l & 15, fkc = l >> 4;
  // read-side chunk swizzle: chunk' = fkc ^ ((frow>>1)&3)  (fixed per lane)
  const uint32_t chunk = (uint32_t)((fkc ^ ((frow >> 1) & 3)) * 16);
  const uint32_t aBase = (uint32_t)(wm + frow) * 64 + chunk;           // +mi*1024 +kh*16384 +buf*32768
  const uint32_t bBase = 65536u + (uint32_t)(wn + frow) * 64 + chunk;  // +ni*1024 +kh*16384 +buf*32768
  char* lW = smem + (uint32_t)w * 1024u;   // per-wave staging dest base
  const int NIT = K >> 7;                  // iterations of 2 K-tiles; K % 128 == 0

#define LDSA(kh_, buf_, half_) (lW + ((buf_) * 32768u + (kh_) * 16384u + (half_) * 8192u))
#define LDSB(kh_, buf_, half_) (lW + (65536u + (buf_) * 32768u + (kh_) * 16384u + (half_) * 8192u))
// off_ is the FULL K-offset in elements (tile*64 + kh*32); kh_ selects the LDS
// destination region only.
#define STG_A(off_, kh_, buf_) do { \
    glds16(aR0 + (off_), LDSA(kh_, buf_, 0)); \
    glds16(aR1 + (off_), LDSA(kh_, buf_, 1)); } while (0)
#define STG_B(off_, kh_, buf_) do { \
    glds16(bR0 + (off_), LDSB(kh_, buf_, 0)); \
    glds16(bR1 + (off_), LDSB(kh_, buf_, 1)); } while (0)
#define RD_A(mi_, kh_, buf_) \
    (*reinterpret_cast<const bf16x8*>(smem + (aBase + (mi_) * 1024u + (kh_) * 16384u + (buf_) * 32768u)))
#define RD_B(ni_, kh_, buf_) \
    (*reinterpret_cast<const bf16x8*>(smem + (bBase + (ni_) * 1024u + (kh_) * 16384u + (buf_) * 32768u)))
#define MFMA16(m0_) do { \
    acc[(m0_)+0][0] = __builtin_amdgcn_mfma_f32_16x16x32_bf16(a0, b0, acc[(m0_)+0][0], 0, 0, 0); \
    acc[(m0_)+1][0] = __builtin_amdgcn_mfma_f32_16x16x32_bf16(a1, b0, acc[(m0_)+1][0], 0, 0, 0); \
    acc[(m0_)+2][0] = __builtin_amdgcn_mfma_f32_16x16x32_bf16(a2, b0, acc[(m0_)+2][0], 0, 0, 0); \
    acc[(m0_)+3][0] = __builtin_amdgcn_mfma_f32_16x16x32_bf16(a3, b0, acc[(m0_)+3][0], 0, 0, 0); \
    acc[(m0_)+0][1] = __builtin_amdgcn_mfma_f32_16x16x32_bf16(a0, b1, acc[(m0_)+0][1], 0, 0, 0); \
    acc[(m0_)+1][1] = __builtin_amdgcn_mfma_f32_16x16x32_bf16(a1, b1, acc[(m0_)+1][1], 0, 0, 0); \
    acc[(m0_)+2][1] = __builtin_amdgcn_mfma_f32_16x16x32_bf16(a2, b1, acc[(m0_)+2][1], 0, 0, 0); \
    acc[(m0_)+3][1] = __builtin_amdgcn_mfma_f32_16x16x32_bf16(a3, b1, acc[(m0_)+3][1], 0, 0, 0); \
    acc[(m0_)+0][2] = __builtin_amdgcn_mfma_f32_16x16x32_bf16(a0, b2, acc[(m0_)+0][2], 0, 0, 0); \
    acc[(m0_)+1][2] = __builtin_amdgcn_mfma_f32_16x16x32_bf16(a1, b2, acc[(m0_)+1][2], 0, 0, 0); \
    acc[(m0_)+2][2] = __builtin_amdgcn_mfma_f32_16x16x32_bf16(a2, b2, acc[(m0_)+2][2], 0, 0, 0); \
    acc[(m0_)+3][2] = __builtin_amdgcn_mfma_f32_16x16x32_bf16(a3, b2, acc[(m0_)+3][2], 0, 0, 0); \
    acc[(m0_)+0][3] = __builtin_amdgcn_mfma_f32_16x16x32_bf16(a0, b3, acc[(m0_)+0][3], 0, 0, 0); \
    acc[(m0_)+1][3] = __builtin_amdgcn_mfma_f32_16x16x32_bf16(a1, b3, acc[(m0_)+1][3], 0, 0, 0); \
    acc[(m0_)+2][3] = __builtin_amdgcn_mfma_f32_16x16x32_bf16(a2, b3, acc[(m0_)+2][3], 0, 0, 0); \
    acc[(m0_)+3][3] = __builtin_amdgcn_mfma_f32_16x16x32_bf16(a3, b3, acc[(m0_)+3][3], 0, 0, 0); \
  } while (0)
#define PH_RD8(kh_, buf_) do { \
    a0 = RD_A(0, kh_, buf_); a1 = RD_A(1, kh_, buf_); \
    a2 = RD_A(2, kh_, buf_); a3 = RD_A(3, kh_, buf_); \
    b0 = RD_B(0, kh_, buf_); b1 = RD_B(1, kh_, buf_); \
    b2 = RD_B(2, kh_, buf_); b3 = RD_B(3, kh_, buf_); } while (0)
#define PH_RD4(kh_, buf_) do { \
    a0 = RD_A(4, kh_, buf_); a1 = RD_A(5, kh_, buf_); \
    a2 = RD_A(6, kh_, buf_); a3 = RD_A(7, kh_, buf_); } while (0)
// ONE barrier per phase: data-ready gate, then prioritized MFMA (no trailing
// barrier -> next phase's RD/STG may be interleaved with this MFMA cluster).
#define MFMA_PH(m0_) do { \
    BARRIER(); \
    __builtin_amdgcn_s_setprio(1); \
    MFMA16(m0_); \
    __builtin_amdgcn_s_setprio(0); } while (0)

  // ---- prologue: tile0 kh0@0 kh1@32 + tile1 kh0@64 --------------------------
  STG_A(0, 0, 0); STG_B(0, 0, 0); STG_A(32, 1, 0); STG_B(32, 1, 0);
  STG_A(64, 0, 1); STG_B(64, 0, 1);
  VMCNT(4);

  bf16x8 a0, a1, a2, a3, b0, b1, b2, b3;
  BARRIER();   // BAR0: t0 data published to all waves

  // ---- steady state: branch-free, 2 K-tiles / iteration ----------------------
  for (int it = 0; it < NIT - 1; ++it) {
    // ===== tile t0 (buf 0) =====
    PH_RD8(0, 0); STG_A(96, 1, 1);            MFMA_PH(0);   // P1
    PH_RD4(0, 0); STG_B(96, 1, 1); VMCNT(8);  MFMA_PH(4);   // P2 -> t0.kh1 ready
    PH_RD8(1, 0); STG_A(128, 0, 0);           MFMA_PH(0);   // P3
    PH_RD4(1, 0); STG_B(128, 0, 0); VMCNT(8); MFMA_PH(4);   // P4 -> t1.kh0 ready
    // ===== tile t1 (buf 1) =====
    PH_RD8(0, 1); STG_A(160, 1, 0);           MFMA_PH(0);   // P5
    PH_RD4(0, 1); STG_B(160, 1, 0); VMCNT(8); MFMA_PH(4);   // P6 -> t1.kh1 ready
    PH_RD8(1, 1); STG_A(192, 0, 1);           MFMA_PH(0);   // P7
    PH_RD4(1, 1); STG_B(192, 0, 1); VMCNT(8); MFMA_PH(4);   // P8 -> t2.kh0 ready
    aR0 += 128; aR1 += 128; bR0 += 128; bR1 += 128;
  }

  // ---- tail: last 2 tiles (t0 buf0 / t1 buf1); only A/B(t1,kh1)@96 to stage --
  PH_RD8(0, 0); STG_A(96, 1, 1);            MFMA_PH(0);
  PH_RD4(0, 0); STG_B(96, 1, 1); VMCNT(8);  MFMA_PH(4);     // -> t0.kh1 ready
  PH_RD8(1, 0);                             MFMA_PH(0);
  PH_RD4(1, 0); VMCNT(4);                   MFMA_PH(4);     // -> t1.kh0 ready
  PH_RD8(0, 1);                             MFMA_PH(0);
  PH_RD4(0, 1); VMCNT(0);                   MFMA_PH(4);     // -> t1.kh1 ready
  PH_RD8(1, 1);                             MFMA_PH(0);
  PH_RD4(1, 1);                             MFMA_PH(4);
#undef LDSA
#undef LDSB
#undef STG_A
#undef STG_B
#undef RD_A
#undef RD_B
#undef MFMA16
#undef PH_RD8
#undef PH_RD4
#undef MFMA_PH
}

// staging source-column swizzle (involution with read side): g = (tid&3)^((tid>>3)&3)
__device__ __forceinline__ int stage_co() {
  const int tid = threadIdx.x;
  return (((tid & 3) ^ ((tid >> 3) & 3)) * 8);
}

// ---- stage A: kv^T, block-uniform split-store into k0T / vT ------------------
__global__ __launch_bounds__(512, 2) void k_gemm_kv(
    const uint16_t* __restrict__ W,    // wqkb 4096x2048
    const uint16_t* __restrict__ X,    // xb   8192x2048
    uint16_t* __restrict__ k0T,        // 2048x8192
    uint16_t* __restrict__ vT)         // 2048x8192
{
  const int tid = threadIdx.x;
  const int bm = blockIdx.y, bn = blockIdx.x;
  const int r0 = tid >> 2, co = stage_co();
  const uint16_t* aR0 = W + (size_t)(bm * 256 + r0) * 2048 + co;
  const uint16_t* aR1 = W + (size_t)(bm * 256 + 128 + r0) * 2048 + co;
  const uint16_t* bR0 = X + (size_t)(bn * 256 + r0) * 2048 + co;
  const uint16_t* bR1 = X + (size_t)(bn * 256 + 128 + r0) * 2048 + co;
  f32x4 acc[8][4];
#pragma unroll
  for (int i = 0; i < 8; ++i)
#pragma unroll
    for (int j = 0; j < 4; ++j) acc[i][j] = (f32x4){0.f, 0.f, 0.f, 0.f};
  gemm256_core(aR0, aR1, bR0, bR1, 2048, acc);
  const int w = tid >> 6, l = tid & 63;
  const int wm = (w >> 2) * 128, wn = (w & 3) * 64;
  const int cr = (l >> 4) * 4, cc = l & 15;
  uint16_t* Cb = (bm < 8) ? k0T : vT;
  const int rb = (bm & 7) * 256;
#pragma unroll
  for (int mi = 0; mi < 8; ++mi)
#pragma unroll
    for (int ni = 0; ni < 4; ++ni)
#pragma unroll
      for (int g = 0; g < 4; ++g) {
        int lr = rb + wm + mi * 16 + cr + g;
        int bt = bn * 256 + wn + ni * 16 + cc;
        Cb[(size_t)lr * 8192 + bt] = f2bf(acc[mi][ni][g]);
      }
}

// ---- generic batched A@B^T (both K-contig), scaled bf16 store ----------------
__global__ __launch_bounds__(512, 2) void k_gemm_bt(
    const uint16_t* __restrict__ A, int lda, long sA,
    const uint16_t* __restrict__ B, int ldb, long sB,
    uint16_t* __restrict__ C, int ldc, long sC,
    int K, float scale)
{
  const int z = blockIdx.z;
  A += (size_t)z * sA; B += (size_t)z * sB; C += (size_t)z * sC;
  const int tid = threadIdx.x;
  const int bm = blockIdx.y, bn = blockIdx.x;
  const int r0 = tid >> 2, co = stage_co();
  const uint16_t* aR0 = A + (size_t)(bm * 256 + r0) * lda + co;
  const uint16_t* aR1 = A + (size_t)(bm * 256 + 128 + r0) * lda + co;
  const uint16_t* bR0 = B + (size_t)(bn * 256 + r0) * ldb + co;
  const uint16_t* bR1 = B + (size_t)(bn * 256 + 128 + r0) * ldb + co;
  f32x4 acc[8][4];
#pragma unroll
  for (int i = 0; i < 8; ++i)
#pragma unroll
    for (int j = 0; j < 4; ++j) acc[i][j] = (f32x4){0.f, 0.f, 0.f, 0.f};
  gemm256_core(aR0, aR1, bR0, bR1, K, acc);
  const int w = tid >> 6, l = tid & 63;
  const int wm = (w >> 2) * 128, wn = (w & 3) * 64;
  const int cr = (l >> 4) * 4, cc = l & 15;
#pragma unroll
  for (int mi = 0; mi < 8; ++mi)
#pragma unroll
    for (int ni = 0; ni < 4; ++ni)
#pragma unroll
      for (int g = 0; g < 4; ++g) {
        int grow = bm * 256 + wm + mi * 16 + cr + g;
        int gcol = bn * 256 + wn + ni * 16 + cc;
        C[(size_t)grow * ldc + gcol] = f2bf(acc[mi][ni][g] * scale);
      }
}

// ---- stage D: permuted-A GEMM + fp32 bias/store into d_out -------------------
__device__ __forceinline__ size_t qrow_off(int rr) {
  // rr = b'*2048 + t' ; q row = (b_i, i), b_i=(t'>>4)&3, i=(t'&15)*128+b'*32+(t'>>6)
  int bp = rr >> 11, tp = rr & 2047;
  int bi = (tp >> 4) & 3;
  int i  = (tp & 15) * 128 + bp * 32 + (tp >> 6);
  return ((size_t)bi * 2048 + (size_t)i) * 2048;
}

__global__ __launch_bounds__(512, 2) void k_gemm_out(
    const uint16_t* __restrict__ Q,     // qb (4,2048,2048) bf16
    const uint16_t* __restrict__ W,     // wdb 2048x2048 bf16
    const float*    __restrict__ bias,  // b_dense fp32 (2048)
    float*          __restrict__ Out)   // d_out 8192x2048 fp32
{
  const int tid = threadIdx.x;
  const int bm = blockIdx.y, bn = blockIdx.x;
  const int r0 = tid >> 2, co = stage_co();
  const uint16_t* aR0 = Q + qrow_off(bm * 256 + r0) + co;
  const uint16_t* aR1 = Q + qrow_off(bm * 256 + 128 + r0) + co;
  const uint16_t* bR0 = W + (size_t)(bn * 256 + r0) * 2048 + co;
  const uint16_t* bR1 = W + (size_t)(bn * 256 + 128 + r0) * 2048 + co;
  f32x4 acc[8][4];
#pragma unroll
  for (int i = 0; i < 8; ++i)
#pragma unroll
    for (int j = 0; j < 4; ++j) acc[i][j] = (f32x4){0.f, 0.f, 0.f, 0.f};
  gemm256_core(aR0, aR1, bR0, bR1, 2048, acc);
  const int w = tid >> 6, l = tid & 63;
  const int wm = (w >> 2) * 128, wn = (w & 3) * 64;
  const int cr = (l >> 4) * 4, cc = l & 15;
#pragma unroll
  for (int mi = 0; mi < 8; ++mi)
#pragma unroll
    for (int ni = 0; ni < 4; ++ni)
#pragma unroll
      for (int g = 0; g < 4; ++g) {
        int grow = bm * 256 + wm + mi * 16 + cr + g;
        int gcol = bn * 256 + wn + ni * 16 + cc;
        Out[(size_t)grow * 2048 + gcol] = acc[mi][ni][g] + bias[gcol];
      }
}

// ---- transpose vT (2048x8192) -> Vn (8192x2048) ------------------------------
__global__ __launch_bounds__(256) void k_transpose(
    const uint16_t* __restrict__ src, uint16_t* __restrict__ dst)
{
  __shared__ uint16_t tile[64][65];
  const int tid = threadIdx.x;
  const int bx = blockIdx.x;
  const int by = blockIdx.y;
  const int cu = tid & 31, r0 = tid >> 5;
#pragma unroll
  for (int p = 0; p < 8; ++p) {
    int r = p * 8 + r0;
    uint32_t v = *reinterpret_cast<const uint32_t*>(
        &src[(size_t)(by * 64 + r) * 8192 + bx * 64 + cu * 2]);
    tile[r][cu * 2]     = (uint16_t)(v & 0xffffu);
    tile[r][cu * 2 + 1] = (uint16_t)(v >> 16);
  }
  __syncthreads();
#pragma unroll
  for (int p = 0; p < 8; ++p) {
    int r = p * 8 + r0;
    uint32_t lo = tile[cu * 2][r], hi = tile[cu * 2 + 1][r];
    *reinterpret_cast<uint32_t*>(
        &dst[(size_t)(bx * 64 + r) * 2048 + by * 64 + cu * 2]) = lo | (hi << 16);
  }
}

// ---- row softmax (bf16 in place), 1 block per row of 2048 --------------------
__global__ __launch_bounds__(256) void k_softmax(uint16_t* __restrict__ s)
{
  uint16_t* p = s + (size_t)blockIdx.x * 2048;
  const int tid = threadIdx.x;
  uint4 raw = reinterpret_cast<const uint4*>(p)[tid];
  uint32_t u[4] = {raw.x, raw.y, raw.z, raw.w};
  float x[8];
#pragma unroll
  for (int i = 0; i < 4; ++i) {
    x[2 * i]     = bf2f((uint16_t)(u[i] & 0xffffu));
    x[2 * i + 1] = bf2f((uint16_t)(u[i] >> 16));
  }
  float m = x[0];
#pragma unroll
  for (int i = 1; i < 8; ++i) m = fmaxf(m, x[i]);
#pragma unroll
  for (int o = 32; o; o >>= 1) m = fmaxf(m, __shfl_xor(m, o, 64));
  __shared__ float redm[4], reds[4];
  if ((tid & 63) == 0) redm[tid >> 6] = m;
  __syncthreads();
  m = fmaxf(fmaxf(redm[0], redm[1]), fmaxf(redm[2], redm[3]));
  float sum = 0.f;
#pragma unroll
  for (int i = 0; i < 8; ++i) { x[i] = __expf(x[i] - m); sum += x[i]; }
#pragma unroll
  for (int o = 32; o; o >>= 1) sum += __shfl_xor(sum, o, 64);
  if ((tid & 63) == 0) reds[tid >> 6] = sum;
  __syncthreads();
  sum = reds[0] + reds[1] + reds[2] + reds[3];
  float inv = 1.0f / sum;
  uint32_t ou[4];
#pragma unroll
  for (int i = 0; i < 4; ++i) {
    uint32_t lo = f2bf(x[2 * i] * inv);
    uint32_t hi = f2bf(x[2 * i + 1] * inv);
    ou[i] = lo | (hi << 16);
  }
  reinterpret_cast<uint4*>(p)[tid] = make_uint4(ou[0], ou[1], ou[2], ou[3]);
}

// ------------------------------------------------------------------------------
extern "C" void kernel_launch(void* const* d_in, const int* in_sizes, int n_in,
                              void* d_out, int out_size, void* d_ws, size_t ws_size,
                              hipStream_t stream) {
  const float* x       = (const float*)d_in[0];
  const float* w_qk    = (const float*)d_in[1];
  const float* w_dense = (const float*)d_in[2];
  const float* b_dense = (const float*)d_in[3];
  float* out = (float*)d_out;

  static int attr_done = 0;
  if (!attr_done) {
    (void)hipFuncSetAttribute(reinterpret_cast<const void*>(k_gemm_kv),
                              hipFuncAttributeMaxDynamicSharedMemorySize, 131072);
    (void)hipFuncSetAttribute(reinterpret_cast<const void*>(k_gemm_bt),
                              hipFuncAttributeMaxDynamicSharedMemorySize, 131072);
    (void)hipFuncSetAttribute(reinterpret_cast<const void*>(k_gemm_out),
                              hipFuncAttributeMaxDynamicSharedMemorySize, 131072);
    attr_done = 1;
  }

  const size_t NX = 4ull * 2048 * 2048;
  const size_t NW = 4096ull * 2048;
  const size_t ND = 2048ull * 2048;

  // d_ws layout (bf16): xb | wqkb | wdb | k0T | vT   (126 MB peak)
  uint16_t* xb   = (uint16_t*)d_ws;
  uint16_t* wqkb = xb + NX;
  uint16_t* wdb  = wqkb + NW;
  uint16_t* k0T  = wdb + ND;
  uint16_t* vT   = k0T + NX;
  uint16_t* qb   = xb;                    // alias: xb dead after stage A
  uint16_t* Vn   = (uint16_t*)d_out;      // d_out as scratch (dead before D)
  uint16_t* sb   = Vn + NX;

  const float scale = (float)(1.0 / sqrt(0.5 * 2048.0 * 2047.0));

  k_cast_all<<<dim3((NX4 + NW4 + ND4) / 256), 256, 0, stream>>>(x, w_qk, w_dense, xb);

  // A: kv^T  (M=4096 e, N=8192 bt, K=2048)
  k_gemm_kv<<<dim3(32, 16), 512, 131072, stream>>>(wqkb, xb, k0T, vT);
  // T: vT -> Vn
  k_transpose<<<dim3(128, 32), 256, 0, stream>>>(vT, Vn);
  // B: s = scale * k0T @ Vn^T
  k_gemm_bt<<<dim3(8, 8, 4), 512, 131072, stream>>>(
      k0T, 8192, 2048L, Vn, 2048, 2048L * 2048L, sb, 2048, 2048L * 2048L, 2048, scale);
  // S: softmax rows
  k_softmax<<<dim3(8192), 256, 0, stream>>>(sb);
  // C: q = a @ vT^T
  k_gemm_bt<<<dim3(8, 8, 4), 512, 131072, stream>>>(
      sb, 2048, 2048L * 2048L, vT, 8192, 2048L, qb, 2048, 2048L * 2048L, 2048, 1.0f);
  // D: out = perm(q) @ w_dense^T + bias -> fp32
  k_gemm_out<<<dim3(8, 32), 512, 131072, stream>>>(qb, wdb, b_dense, out);
}